// Round 9
// baseline (294.684 us; speedup 1.0000x reference)
//
#include <hip/hip_runtime.h>
#include <math.h>

namespace {
constexpr int B_ = 32, I_ = 2048, J_ = 64, D_ = 8, E_ = 16;
constexpr int WAVES = 8, THREADS = 512;      // 4 batch-groups x 2 j-halves
constexpr int BPW = 4;                       // batches per wave (reg accum)
constexpr int BBLK = 16;                     // batches per block
constexpr int PART_STRIDE = BBLK * J_ * E_;  // 16384 floats per block slot
constexpr int VSZ = B_ * J_ * E_;            // 32768
constexpr int HQ = 1024;                     // quads per W half-tile (16 KB)
}

// async global->LDS, 16B/lane. LDS dest = wave-uniform base + lane*16; the
// XOR-swizzle lives in the pre-permuted global source (both-sides rule).
__device__ __forceinline__ void gload_lds16(const float* g, float* l) {
  __builtin_amdgcn_global_load_lds(
      (const __attribute__((address_space(1))) void*)g,
      (__attribute__((address_space(3))) void*)l, 16, 0, 0);
}

// counted-vmcnt barrier: wait own staging to depth N (NEVER 0 in the loop),
// raw s_barrier (no vmcnt drain like __syncthreads), pin scheduler.
#define WAITB(N)                                          \
  asm volatile("s_waitcnt vmcnt(" #N ")" ::: "memory");   \
  __builtin_amdgcn_s_barrier();                           \
  __builtin_amdgcn_sched_barrier(0);

// read this wave's 4 x-values for one tile-half from the LDS x slot
// (uniform address per wave -> broadcast, conflict-free)
#define XFILL(XH, XSRC, HALF)                                               \
  _Pragma("unroll") for (int bb = 0; bb < BPW; ++bb) {                      \
    const float4 t4 = *reinterpret_cast<const float4*>(                     \
        (XSRC) + ((g * BPW + bb) * 2 + (HALF)) * 4);                        \
    XH[bb][0] = t4.x; XH[bb][1] = t4.y;                                     \
    XH[bb][2] = t4.z; XH[bb][3] = t4.w;                                     \
  }

// FMA over one 16 KB W half-tile; all indices compile-time (rule #20)
#define HALF_FMA(TGT, XH, BUF)                                              \
  _Pragma("unroll") for (int dd = 0; dd < 4; ++dd) {                        \
    _Pragma("unroll") for (int c = 0; c < 2; ++c) {                         \
      const int L = lbase + dd * 4 + c;                                     \
      const float4 quad =                                                   \
          *reinterpret_cast<const float4*>((BUF) + (size_t)(L ^ sw) * 4);   \
      _Pragma("unroll") for (int bb = 0; bb < BPW; ++bb) {                  \
        TGT[bb][c * 4 + 0] = fmaf(XH[bb][dd], quad.x, TGT[bb][c * 4 + 0]);  \
        TGT[bb][c * 4 + 1] = fmaf(XH[bb][dd], quad.y, TGT[bb][c * 4 + 1]);  \
        TGT[bb][c * 4 + 2] = fmaf(XH[bb][dd], quad.z, TGT[bb][c * 4 + 2]);  \
        TGT[bb][c * 4 + 3] = fmaf(XH[bb][dd], quad.w, TGT[bb][c * 4 + 3]);  \
      }                                                                     \
    }                                                                       \
  }

// One routing pass. Ring-3 pipeline over 16 KB W half-tiles, schedule per
// half h: [vmcnt(N) | s_barrier | compute h | issue stage h+2]. Stage h+2
// (issued at half h) targets buf (h+2)%3 = (h-1)%3, whose reads finished in
// half h-1 BEFORE that half's trailing barrier -> WAR-safe. vmcnt counts
// (per-wave FIFO): even halves need S(2t)+x(t) retired, younger = S(2t+1)
// [2 ops] -> vmcnt(2); odd halves need S(2t+1), younger = S(2t+2)+x(t+1)
// [3 ops] -> vmcnt(3). x rides the same pipeline: one gload_lds per tile
// into a ping-pong LDS slot (512 B), read back via broadcast ds_read_b128.
template <int MODE, int NIT>
__global__ __launch_bounds__(THREADS, 4) void caps_pass(
    const float* __restrict__ x, const float* __restrict__ W,
    const float* __restrict__ v, float* __restrict__ partial) {
  __shared__ float Wl[3][HQ * 4];    // 3 x 16 KiB W half-tile ring
  __shared__ float xlds[2][128];     // x ping-pong: [16 batches][2 halves][4]
  __shared__ float sm[2][WAVES][4];  // cross-half softmax sums (t parity)
  const int tid = threadIdx.x;
  const int w = tid >> 6, lane = tid & 63;
  const int jl = lane & 31, h = lane >> 5;
  const int g = w >> 1, jh = w & 1;
  const int j = jh * 32 + jl;
  const int ic = (int)blockIdx.x >> 1;
  const int bh = (int)blockIdx.x & 1;
  const int b0 = bh * BBLK + g * BPW;
  const int i0 = ic * NIT;
  const int sw = jl & 7;
  const int NH = 2 * NIT;
  const int lbase = j * 16 + h * 2;

  float vv[BPW][8];
  if (MODE == 1) {
#pragma unroll
    for (int bb = 0; bb < BPW; ++bb) {
      const float4* vp = reinterpret_cast<const float4*>(
          v + ((size_t)(b0 + bb) * J_ + j) * E_ + h * 8);
      const float4 t0 = vp[0], t1 = vp[1];
      vv[bb][0] = t0.x; vv[bb][1] = t0.y; vv[bb][2] = t0.z; vv[bb][3] = t0.w;
      vv[bb][4] = t1.x; vv[bb][5] = t1.y; vv[bb][6] = t1.z; vv[bb][7] = t1.w;
    }
  }

  float acc[BPW][8];
#pragma unroll
  for (int bb = 0; bb < BPW; ++bb)
#pragma unroll
    for (int e = 0; e < 8; ++e) acc[bb][e] = 0.0f;

  // W half-tile stage: 1024 quads = 8 waves x 2 insts x 64 lanes, 2 vmem ops
  auto stage = [&](int hh, float* dst) {
    const int i = i0 + (hh >> 1);
    const int d0q = (hh & 1) * 16;
    const float* Wt = W + ((size_t)i * 2048 + d0q) * 4;
#pragma unroll
    for (int it = 0; it < 2; ++it) {
      const int p = (w * 2 + it) * 64 + lane;
      const int pp = p ^ ((p >> 4) & 7);
      const int src = (pp >> 4) * 32 + (pp & 15);
      gload_lds16(Wt + (size_t)src * 4, dst + p * 4);
    }
  };
  // x stage for tile ti: 512 B via lanes 0..31 (all waves issue the same op
  // redundantly -> identical bytes, benign; keeps vmcnt counts wave-uniform).
  // Global side is per-lane gather; LDS side is base + lane*16 (linear).
  auto stage_x = [&](int ti, float* dst) {
    const int i = i0 + ti;
    const int bl = lane >> 1, hf = lane & 1;
    if (lane < 32)
      gload_lds16(x + ((size_t)(bh * BBLK + bl) * I_ + i) * D_ + hf * 4,
                  dst + lane * 4);
  };

  // prologue (queue: [x0(1), S0(2), S1(2)] -> first WAITB(2) retires x0+S0)
  float* xcur = xlds[0];
  float* xnxt = xlds[1];
  stage_x(0, xcur);
  stage(0, Wl[0]);
  stage(1, Wl[1]);
  float* WE = Wl[0];
  float* WO = Wl[1];
  float* WS = Wl[2];

  float uh[BPW][8];

#pragma unroll 1
  for (int t = 0; t < NIT; ++t) {
    // ---------- even half (d 0..3) ----------
    WAITB(2)
    {
      float xh[BPW][4];
      XFILL(xh, xcur, 0)
      if (MODE == 0) {
        HALF_FMA(acc, xh, WE)
      } else {
#pragma unroll
        for (int bb = 0; bb < BPW; ++bb)
#pragma unroll
          for (int e = 0; e < 8; ++e) uh[bb][e] = 0.0f;
        HALF_FMA(uh, xh, WE)
      }
    }
    if (2 * t + 2 < NH) stage(2 * t + 2, WS);
    if (t + 1 < NIT) stage_x(t + 1, xnxt);

    // ---------- odd half (d 4..7) ----------
    WAITB(3)
    {
      float xh[BPW][4];
      XFILL(xh, xcur, 1)
      if (MODE == 0) {
        HALF_FMA(acc, xh, WO)
      } else {
        HALF_FMA(uh, xh, WO)
        // softmax over j: 32 lanes in-wave + partner-wave exchange via sm.
        const int par = t & 1;
        float pr[BPW], ssum[BPW];
#pragma unroll
        for (int bb = 0; bb < BPW; ++bb) {
          float l0 = 0.f, l1 = 0.f;
#pragma unroll
          for (int e = 0; e < 8; e += 2) {
            l0 = fmaf(uh[bb][e + 0], vv[bb][e + 0], l0);
            l1 = fmaf(uh[bb][e + 1], vv[bb][e + 1], l1);
          }
          float lg = l0 + l1;
          lg += __shfl_xor(lg, 32);    // join e-halves
          const float p = __expf(lg);  // |lg| small; fp32 safe w/o max-sub
          float s = p;
          s += __shfl_xor(s, 1);
          s += __shfl_xor(s, 2);
          s += __shfl_xor(s, 4);
          s += __shfl_xor(s, 8);
          s += __shfl_xor(s, 16);
          pr[bb] = p;
          ssum[bb] = s;
        }
        if (lane == 0) {
          float4 t4;
          t4.x = ssum[0]; t4.y = ssum[1]; t4.z = ssum[2]; t4.w = ssum[3];
          *reinterpret_cast<float4*>(&sm[par][w][0]) = t4;
        }
        // lgkm-only barrier: does NOT drain the staging vmcnt queue
        asm volatile("s_waitcnt lgkmcnt(0)" ::: "memory");
        __builtin_amdgcn_s_barrier();
        __builtin_amdgcn_sched_barrier(0);
        const float4 o = *reinterpret_cast<const float4*>(&sm[par][w ^ 1][0]);
        const float c0 = pr[0] / (ssum[0] + o.x);
        const float c1 = pr[1] / (ssum[1] + o.y);
        const float c2 = pr[2] / (ssum[2] + o.z);
        const float c3 = pr[3] / (ssum[3] + o.w);
#pragma unroll
        for (int e = 0; e < 8; ++e) {
          acc[0][e] = fmaf(c0, uh[0][e], acc[0][e]);
          acc[1][e] = fmaf(c1, uh[1][e], acc[1][e]);
          acc[2][e] = fmaf(c2, uh[2][e], acc[2][e]);
          acc[3][e] = fmaf(c3, uh[3][e], acc[3][e]);
        }
      }
    }
    if (2 * t + 3 < NH) stage(2 * t + 3, WE);
    // rotate ring: (WE, WO, WS) <- (WS, WE, WO); swap x slots
    float* tmp = WE; WE = WS; WS = WO; WO = tmp;
    float* xt = xcur; xcur = xnxt; xnxt = xt;
  }

  // partial[block][blocal][j][e]; lane writes e = h*8 .. h*8+7
  const float scale = (MODE == 0) ? (1.0f / 64.0f) : 1.0f;
  float* op = partial + (size_t)blockIdx.x * PART_STRIDE;
#pragma unroll
  for (int bb = 0; bb < BPW; ++bb) {
    float* dst = op + ((size_t)(g * BPW + bb) * J_ + j) * E_ + h * 8;
    float4 t0, t1;
    t0.x = acc[bb][0] * scale; t0.y = acc[bb][1] * scale;
    t0.z = acc[bb][2] * scale; t0.w = acc[bb][3] * scale;
    t1.x = acc[bb][4] * scale; t1.y = acc[bb][5] * scale;
    t1.z = acc[bb][6] * scale; t1.w = acc[bb][7] * scale;
    reinterpret_cast<float4*>(dst)[0] = t0;
    reinterpret_cast<float4*>(dst)[1] = t1;
  }
}

// Sum nic i-chunk partials for one (b, j-octet), squash, emit v.
// mode 0: v1 = squash(s); vsum = v1
// mode 1: vsum += squash(s)
// mode 2: out = squash(s)
__global__ __launch_bounds__(128) void caps_reduce(
    const float* __restrict__ partial, float* __restrict__ v1,
    float* __restrict__ vsum, float* __restrict__ out, const int mode,
    const int nic) {
  const int b = blockIdx.x >> 3;
  const int jg = blockIdx.x & 7;
  const int t = threadIdx.x;
  const int e = t & (E_ - 1);
  const int j = jg * 8 + (t >> 4);
  const int bh = b >> 4;
  const int bb = b & (BBLK - 1);
  const float* p =
      partial + (size_t)bh * PART_STRIDE + (size_t)bb * (J_ * E_) + j * E_ + e;
  float s = 0.0f;
#pragma unroll 8
  for (int icb = 0; icb < nic; ++icb)
    s += p[(size_t)icb * (2 * PART_STRIDE)];
  float sq = s * s;
  sq += __shfl_xor(sq, 1);
  sq += __shfl_xor(sq, 2);
  sq += __shfl_xor(sq, 4);
  sq += __shfl_xor(sq, 8);
  const float scale = sq / ((1.0f + sq) * sqrtf(sq));
  const float vv = s * scale;
  const int idx = (b * J_ + j) * E_ + e;
  if (mode == 0) {
    v1[idx] = vv;
    vsum[idx] = vv;
  } else if (mode == 1) {
    vsum[idx] += vv;
  } else {
    out[idx] = vv;
  }
}

extern "C" void kernel_launch(void* const* d_in, const int* in_sizes, int n_in,
                              void* d_out, int out_size, void* d_ws,
                              size_t ws_size, hipStream_t stream) {
  const float* x = (const float*)d_in[0];
  const float* W = (const float*)d_in[1];
  float* out = (float*)d_out;
  float* partial = (float*)d_ws;

  const size_t need = ((size_t)512 * PART_STRIDE + 2 * VSZ) * sizeof(float);
  const bool big = ws_size >= need;
  const int nblk = big ? 512 : 256;
  const int nic = big ? 256 : 128;
  float* v1 = partial + (size_t)nblk * PART_STRIDE;
  float* vsum = v1 + VSZ;

  if (big) {
    caps_pass<0, 8><<<nblk, THREADS, 0, stream>>>(x, W, nullptr, partial);
    caps_reduce<<<B_ * 8, 128, 0, stream>>>(partial, v1, vsum, out, 0, nic);
    caps_pass<1, 8><<<nblk, THREADS, 0, stream>>>(x, W, v1, partial);
    caps_reduce<<<B_ * 8, 128, 0, stream>>>(partial, v1, vsum, out, 1, nic);
    caps_pass<1, 8><<<nblk, THREADS, 0, stream>>>(x, W, vsum, partial);
    caps_reduce<<<B_ * 8, 128, 0, stream>>>(partial, v1, vsum, out, 2, nic);
  } else {
    caps_pass<0, 16><<<nblk, THREADS, 0, stream>>>(x, W, nullptr, partial);
    caps_reduce<<<B_ * 8, 128, 0, stream>>>(partial, v1, vsum, out, 0, nic);
    caps_pass<1, 16><<<nblk, THREADS, 0, stream>>>(x, W, v1, partial);
    caps_reduce<<<B_ * 8, 128, 0, stream>>>(partial, v1, vsum, out, 1, nic);
    caps_pass<1, 16><<<nblk, THREADS, 0, stream>>>(x, W, vsum, partial);
    caps_reduce<<<B_ * 8, 128, 0, stream>>>(partial, v1, vsum, out, 2, nic);
  }
}

// Round 10
// 178.082 us; speedup vs baseline: 1.6548x; 1.6548x over previous
//
#include <hip/hip_runtime.h>
#include <math.h>

namespace {
constexpr int B_ = 32, I_ = 2048, J_ = 64, D_ = 8, E_ = 16;
constexpr int WAVES = 8, THREADS = 512;      // 4 batch-groups x 2 j-halves
constexpr int BPW = 4;                       // batches per wave (reg accum)
constexpr int BBLK = 16;                     // batches per block
constexpr int PART_STRIDE = BBLK * J_ * E_;  // 16384 floats per block slot
constexpr int VSZ = B_ * J_ * E_;            // 32768
constexpr int HQ = 1024;                     // quads per W half-tile (16 KB)
}

// async global->LDS, 16B/lane. LDS dest = wave-uniform base + lane*16; the
// XOR-swizzle lives in the pre-permuted global source (both-sides rule).
__device__ __forceinline__ void gload_lds16(const float* g, float* l) {
  __builtin_amdgcn_global_load_lds(
      (const __attribute__((address_space(1))) void*)g,
      (__attribute__((address_space(3))) void*)l, 16, 0, 0);
}

// counted-vmcnt barrier: wait own staging to depth N (NEVER 0 in the loop),
// raw s_barrier (no vmcnt drain like __syncthreads), pin scheduler.
#define WAITB(N)                                          \
  asm volatile("s_waitcnt vmcnt(" #N ")" ::: "memory");   \
  __builtin_amdgcn_s_barrier();                           \
  __builtin_amdgcn_sched_barrier(0);

// read this wave's 4 x-values for one tile-half from the LDS x slot
// (uniform address per wave -> broadcast, conflict-free)
#define XFILL(XH, XSRC, HALF)                                               \
  _Pragma("unroll") for (int bb = 0; bb < BPW; ++bb) {                      \
    const float4 t4 = *reinterpret_cast<const float4*>(                     \
        (XSRC) + ((g * BPW + bb) * 2 + (HALF)) * 4);                        \
    XH[bb][0] = t4.x; XH[bb][1] = t4.y;                                     \
    XH[bb][2] = t4.z; XH[bb][3] = t4.w;                                     \
  }

// FMA over one 16 KB W half-tile; all indices compile-time (rule #20)
#define HALF_FMA(TGT, XH, BUF)                                              \
  _Pragma("unroll") for (int dd = 0; dd < 4; ++dd) {                        \
    _Pragma("unroll") for (int c = 0; c < 2; ++c) {                         \
      const int L = lbase + dd * 4 + c;                                     \
      const float4 quad =                                                   \
          *reinterpret_cast<const float4*>((BUF) + (size_t)(L ^ sw) * 4);   \
      _Pragma("unroll") for (int bb = 0; bb < BPW; ++bb) {                  \
        TGT[bb][c * 4 + 0] = fmaf(XH[bb][dd], quad.x, TGT[bb][c * 4 + 0]);  \
        TGT[bb][c * 4 + 1] = fmaf(XH[bb][dd], quad.y, TGT[bb][c * 4 + 1]);  \
        TGT[bb][c * 4 + 2] = fmaf(XH[bb][dd], quad.z, TGT[bb][c * 4 + 2]);  \
        TGT[bb][c * 4 + 3] = fmaf(XH[bb][dd], quad.w, TGT[bb][c * 4 + 3]);  \
      }                                                                     \
    }                                                                       \
  }

// One routing pass. Ring-3 pipeline over 16 KB W half-tiles, schedule per
// half h: [vmcnt(N) | s_barrier | compute h | issue stage h+2]. Stage h+2
// (issued at half h) targets buf (h+2)%3 = (h-1)%3, whose reads finished in
// half h-1 BEFORE that half's trailing barrier -> WAR-safe. vmcnt counts
// (per-wave FIFO): even halves need S(2t)+x(t) retired, younger = S(2t+1)
// [2 ops] -> vmcnt(2); odd halves need S(2t+1), younger = S(2t+2)+x(t+1)
// [3 ops] -> vmcnt(3). x rides the same pipeline: one gload_lds per tile
// into a ping-pong LDS slot (512 B), read back via broadcast ds_read_b128.
// __launch_bounds__(512,2): rounds 2/5/8 prove this body compiles ~88 VGPR
// spill-free at this bound; every forced cap below ~160 (rounds 3/4/6/7/9)
// demoted arrays to scratch (rule #20 class) and burned 100+ MB/pass.
template <int MODE, int NIT>
__global__ __launch_bounds__(THREADS, 2) void caps_pass(
    const float* __restrict__ x, const float* __restrict__ W,
    const float* __restrict__ v, float* __restrict__ partial) {
  __shared__ float Wl[3][HQ * 4];    // 3 x 16 KiB W half-tile ring
  __shared__ float xlds[2][128];     // x ping-pong: [16 batches][2 halves][4]
  __shared__ float sm[2][WAVES][4];  // cross-half softmax sums (t parity)
  const int tid = threadIdx.x;
  const int w = tid >> 6, lane = tid & 63;
  const int jl = lane & 31, h = lane >> 5;
  const int g = w >> 1, jh = w & 1;
  const int j = jh * 32 + jl;
  const int ic = (int)blockIdx.x >> 1;
  const int bh = (int)blockIdx.x & 1;
  const int b0 = bh * BBLK + g * BPW;
  const int i0 = ic * NIT;
  const int sw = jl & 7;
  const int NH = 2 * NIT;
  const int lbase = j * 16 + h * 2;

  float vv[BPW][8];
  if (MODE == 1) {
#pragma unroll
    for (int bb = 0; bb < BPW; ++bb) {
      const float4* vp = reinterpret_cast<const float4*>(
          v + ((size_t)(b0 + bb) * J_ + j) * E_ + h * 8);
      const float4 t0 = vp[0], t1 = vp[1];
      vv[bb][0] = t0.x; vv[bb][1] = t0.y; vv[bb][2] = t0.z; vv[bb][3] = t0.w;
      vv[bb][4] = t1.x; vv[bb][5] = t1.y; vv[bb][6] = t1.z; vv[bb][7] = t1.w;
    }
  }

  float acc[BPW][8];
#pragma unroll
  for (int bb = 0; bb < BPW; ++bb)
#pragma unroll
    for (int e = 0; e < 8; ++e) acc[bb][e] = 0.0f;

  // W half-tile stage: 1024 quads = 8 waves x 2 insts x 64 lanes, 2 vmem ops
  auto stage = [&](int hh, float* dst) {
    const int i = i0 + (hh >> 1);
    const int d0q = (hh & 1) * 16;
    const float* Wt = W + ((size_t)i * 2048 + d0q) * 4;
#pragma unroll
    for (int it = 0; it < 2; ++it) {
      const int p = (w * 2 + it) * 64 + lane;
      const int pp = p ^ ((p >> 4) & 7);
      const int src = (pp >> 4) * 32 + (pp & 15);
      gload_lds16(Wt + (size_t)src * 4, dst + p * 4);
    }
  };
  // x stage for tile ti: 512 B via lanes 0..31 (all waves issue the same op
  // redundantly -> identical bytes, benign; keeps vmcnt counts wave-uniform).
  // Global side is per-lane gather; LDS side is base + lane*16 (linear).
  auto stage_x = [&](int ti, float* dst) {
    const int i = i0 + ti;
    const int bl = lane >> 1, hf = lane & 1;
    if (lane < 32)
      gload_lds16(x + ((size_t)(bh * BBLK + bl) * I_ + i) * D_ + hf * 4,
                  dst + lane * 4);
  };

  // prologue (queue: [x0(1), S0(2), S1(2)] -> first WAITB(2) retires x0+S0)
  float* xcur = xlds[0];
  float* xnxt = xlds[1];
  stage_x(0, xcur);
  stage(0, Wl[0]);
  stage(1, Wl[1]);
  float* WE = Wl[0];
  float* WO = Wl[1];
  float* WS = Wl[2];

  float uh[BPW][8];

#pragma unroll 1
  for (int t = 0; t < NIT; ++t) {
    // ---------- even half (d 0..3) ----------
    WAITB(2)
    {
      float xh[BPW][4];
      XFILL(xh, xcur, 0)
      if (MODE == 0) {
        HALF_FMA(acc, xh, WE)
      } else {
#pragma unroll
        for (int bb = 0; bb < BPW; ++bb)
#pragma unroll
          for (int e = 0; e < 8; ++e) uh[bb][e] = 0.0f;
        HALF_FMA(uh, xh, WE)
      }
    }
    if (2 * t + 2 < NH) stage(2 * t + 2, WS);
    if (t + 1 < NIT) stage_x(t + 1, xnxt);

    // ---------- odd half (d 4..7) ----------
    WAITB(3)
    {
      float xh[BPW][4];
      XFILL(xh, xcur, 1)
      if (MODE == 0) {
        HALF_FMA(acc, xh, WO)
      } else {
        HALF_FMA(uh, xh, WO)
        // softmax over j: 32 lanes in-wave + partner-wave exchange via sm.
        const int par = t & 1;
        float pr[BPW], ssum[BPW];
#pragma unroll
        for (int bb = 0; bb < BPW; ++bb) {
          float l0 = 0.f, l1 = 0.f;
#pragma unroll
          for (int e = 0; e < 8; e += 2) {
            l0 = fmaf(uh[bb][e + 0], vv[bb][e + 0], l0);
            l1 = fmaf(uh[bb][e + 1], vv[bb][e + 1], l1);
          }
          float lg = l0 + l1;
          lg += __shfl_xor(lg, 32);    // join e-halves
          const float p = __expf(lg);  // |lg| small; fp32 safe w/o max-sub
          float s = p;
          s += __shfl_xor(s, 1);
          s += __shfl_xor(s, 2);
          s += __shfl_xor(s, 4);
          s += __shfl_xor(s, 8);
          s += __shfl_xor(s, 16);
          pr[bb] = p;
          ssum[bb] = s;
        }
        if (lane == 0) {
          float4 t4;
          t4.x = ssum[0]; t4.y = ssum[1]; t4.z = ssum[2]; t4.w = ssum[3];
          *reinterpret_cast<float4*>(&sm[par][w][0]) = t4;
        }
        // lgkm-only barrier: does NOT drain the staging vmcnt queue
        asm volatile("s_waitcnt lgkmcnt(0)" ::: "memory");
        __builtin_amdgcn_s_barrier();
        __builtin_amdgcn_sched_barrier(0);
        const float4 o = *reinterpret_cast<const float4*>(&sm[par][w ^ 1][0]);
        const float c0 = pr[0] / (ssum[0] + o.x);
        const float c1 = pr[1] / (ssum[1] + o.y);
        const float c2 = pr[2] / (ssum[2] + o.z);
        const float c3 = pr[3] / (ssum[3] + o.w);
#pragma unroll
        for (int e = 0; e < 8; ++e) {
          acc[0][e] = fmaf(c0, uh[0][e], acc[0][e]);
          acc[1][e] = fmaf(c1, uh[1][e], acc[1][e]);
          acc[2][e] = fmaf(c2, uh[2][e], acc[2][e]);
          acc[3][e] = fmaf(c3, uh[3][e], acc[3][e]);
        }
      }
    }
    if (2 * t + 3 < NH) stage(2 * t + 3, WE);
    // rotate ring: (WE, WO, WS) <- (WS, WE, WO); swap x slots
    float* tmp = WE; WE = WS; WS = WO; WO = tmp;
    float* xt = xcur; xcur = xnxt; xnxt = xt;
  }

  // partial[block][blocal][j][e]; lane writes e = h*8 .. h*8+7
  const float scale = (MODE == 0) ? (1.0f / 64.0f) : 1.0f;
  float* op = partial + (size_t)blockIdx.x * PART_STRIDE;
#pragma unroll
  for (int bb = 0; bb < BPW; ++bb) {
    float* dst = op + ((size_t)(g * BPW + bb) * J_ + j) * E_ + h * 8;
    float4 t0, t1;
    t0.x = acc[bb][0] * scale; t0.y = acc[bb][1] * scale;
    t0.z = acc[bb][2] * scale; t0.w = acc[bb][3] * scale;
    t1.x = acc[bb][4] * scale; t1.y = acc[bb][5] * scale;
    t1.z = acc[bb][6] * scale; t1.w = acc[bb][7] * scale;
    reinterpret_cast<float4*>(dst)[0] = t0;
    reinterpret_cast<float4*>(dst)[1] = t1;
  }
}

// Sum nic i-chunk partials for one (b, j-octet), squash, emit v.
// mode 0: v1 = squash(s); vsum = v1
// mode 1: vsum += squash(s)
// mode 2: out = squash(s)
__global__ __launch_bounds__(128) void caps_reduce(
    const float* __restrict__ partial, float* __restrict__ v1,
    float* __restrict__ vsum, float* __restrict__ out, const int mode,
    const int nic) {
  const int b = blockIdx.x >> 3;
  const int jg = blockIdx.x & 7;
  const int t = threadIdx.x;
  const int e = t & (E_ - 1);
  const int j = jg * 8 + (t >> 4);
  const int bh = b >> 4;
  const int bb = b & (BBLK - 1);
  const float* p =
      partial + (size_t)bh * PART_STRIDE + (size_t)bb * (J_ * E_) + j * E_ + e;
  float s = 0.0f;
#pragma unroll 8
  for (int icb = 0; icb < nic; ++icb)
    s += p[(size_t)icb * (2 * PART_STRIDE)];
  float sq = s * s;
  sq += __shfl_xor(sq, 1);
  sq += __shfl_xor(sq, 2);
  sq += __shfl_xor(sq, 4);
  sq += __shfl_xor(sq, 8);
  const float scale = sq / ((1.0f + sq) * sqrtf(sq));
  const float vv = s * scale;
  const int idx = (b * J_ + j) * E_ + e;
  if (mode == 0) {
    v1[idx] = vv;
    vsum[idx] = vv;
  } else if (mode == 1) {
    vsum[idx] += vv;
  } else {
    out[idx] = vv;
  }
}

extern "C" void kernel_launch(void* const* d_in, const int* in_sizes, int n_in,
                              void* d_out, int out_size, void* d_ws,
                              size_t ws_size, hipStream_t stream) {
  const float* x = (const float*)d_in[0];
  const float* W = (const float*)d_in[1];
  float* out = (float*)d_out;
  float* partial = (float*)d_ws;

  const size_t need = ((size_t)512 * PART_STRIDE + 2 * VSZ) * sizeof(float);
  const bool big = ws_size >= need;
  const int nblk = big ? 512 : 256;
  const int nic = big ? 256 : 128;
  float* v1 = partial + (size_t)nblk * PART_STRIDE;
  float* vsum = v1 + VSZ;

  if (big) {
    caps_pass<0, 8><<<nblk, THREADS, 0, stream>>>(x, W, nullptr, partial);
    caps_reduce<<<B_ * 8, 128, 0, stream>>>(partial, v1, vsum, out, 0, nic);
    caps_pass<1, 8><<<nblk, THREADS, 0, stream>>>(x, W, v1, partial);
    caps_reduce<<<B_ * 8, 128, 0, stream>>>(partial, v1, vsum, out, 1, nic);
    caps_pass<1, 8><<<nblk, THREADS, 0, stream>>>(x, W, vsum, partial);
    caps_reduce<<<B_ * 8, 128, 0, stream>>>(partial, v1, vsum, out, 2, nic);
  } else {
    caps_pass<0, 16><<<nblk, THREADS, 0, stream>>>(x, W, nullptr, partial);
    caps_reduce<<<B_ * 8, 128, 0, stream>>>(partial, v1, vsum, out, 0, nic);
    caps_pass<1, 16><<<nblk, THREADS, 0, stream>>>(x, W, v1, partial);
    caps_reduce<<<B_ * 8, 128, 0, stream>>>(partial, v1, vsum, out, 1, nic);
    caps_pass<1, 16><<<nblk, THREADS, 0, stream>>>(x, W, vsum, partial);
    caps_reduce<<<B_ * 8, 128, 0, stream>>>(partial, v1, vsum, out, 2, nic);
  }
}